// Round 9
// baseline (100.661 us; speedup 1.0000x reference)
//
#include <hip/hip_runtime.h>
#include <hip/hip_bf16.h>

#define NB 64
#define NC 256
#define NL 2048
#define NH 8
#define KW 3
#define LP (NL - KW + 1)  // 2046
#define NCHUNK 16
#define CPC (NC / NCHUNK)  // 16 channels per chunk

typedef float v4f __attribute__((ext_vector_type(4)));

// monotonic float->uint key: order(u) == order(x)
__device__ __forceinline__ unsigned fkey(float x) {
  unsigned b = __float_as_uint(x);
  return (b & 0x80000000u) ? ~b : (b | 0x80000000u);
}

// Kernel 1: conv1d partial sums. Each thread: 4 consecutive l outputs x 8
// heads. Halo comes from a SECOND overlapping v4f load at l0+2 (L1-served,
// no cross-lane shuffle -> pure load->FMA dataflow the compiler can
// software-pipeline). Channel pairs batched: 4 loads issued together.
// Grid (2, NB, NCHUNK=16) = 2048 blocks = 8/CU for max TLP.
__global__ __launch_bounds__(256) void conv_partial(
    const float* __restrict__ src, const float* __restrict__ conv_w,
    float* __restrict__ part) {
  const int t = threadIdx.x;
  const int l0 = blockIdx.x * 1024 + t * 4;
  const int b = blockIdx.y;
  const int cc = blockIdx.z;
  const int c0 = cc * CPC;

  float acc[NH][4];
#pragma unroll
  for (int h = 0; h < NH; ++h)
#pragma unroll
    for (int j = 0; j < 4; ++j) acc[h][j] = 0.f;

  // overlapping-halo load offset; the single thread with l0 == NL-4 clamps
  // to 0 (its halo feeds only outputs >= LP, which are never stored).
  const int off2 = (l0 + 5 < NL) ? 2 : 0;
  const float* sp = src + ((size_t)b * NC + c0) * NL + l0;

#pragma unroll 2
  for (int c = 0; c < CPC; c += 2) {
    // 4 independent loads issued as a batch (no DS ops on the critical path)
    v4f a1 = *(const v4f*)sp;
    v4f a2 = *(const v4f*)(sp + off2);
    v4f b1 = *(const v4f*)(sp + NL);
    v4f b2 = *(const v4f*)(sp + NL + off2);
    sp += 2 * NL;
#pragma unroll
    for (int h = 0; h < NH; ++h) {
      const float* w = conv_w + (h * NC + c0 + c) * KW;  // uniform -> s_load
      const float w0 = w[0], w1 = w[1], w2 = w[2];
      const float w3 = w[3], w4 = w[4], w5 = w[5];
      acc[h][0] = fmaf(a1.x, w0, fmaf(a1.y, w1, fmaf(a1.z, w2, acc[h][0])));
      acc[h][1] = fmaf(a1.y, w0, fmaf(a1.z, w1, fmaf(a1.w, w2, acc[h][1])));
      acc[h][2] = fmaf(a1.z, w0, fmaf(a1.w, w1, fmaf(a2.z, w2, acc[h][2])));
      acc[h][3] = fmaf(a1.w, w0, fmaf(a2.z, w1, fmaf(a2.w, w2, acc[h][3])));
      acc[h][0] = fmaf(b1.x, w3, fmaf(b1.y, w4, fmaf(b1.z, w5, acc[h][0])));
      acc[h][1] = fmaf(b1.y, w3, fmaf(b1.z, w4, fmaf(b1.w, w5, acc[h][1])));
      acc[h][2] = fmaf(b1.z, w3, fmaf(b1.w, w4, fmaf(b2.z, w5, acc[h][2])));
      acc[h][3] = fmaf(b1.w, w3, fmaf(b2.z, w4, fmaf(b2.w, w5, acc[h][3])));
    }
  }
#pragma unroll
  for (int h = 0; h < NH; ++h) {
    float* pr = part + ((size_t)(b * NH + h) * NCHUNK + cc) * NL + l0;
    if (l0 + 3 < LP) {
      *(v4f*)pr = *(v4f*)acc[h];
    } else {
#pragma unroll
      for (int j = 0; j < 4; ++j)
        if (l0 + j < LP) pr[j] = acc[h][j];
    }
  }
}

// Kernel 2 (R6-proven, now 16 partial streams): one 256-thread block per
// (b,h). Sum partials (+bias) into LDS (part is L2/L3-hot), BN stats, exact
// radix-select of the k-th largest (stable ties like lax.top_k), sigmoid
// mask, 3-tap box sum, write cw*M into the xi row.
__global__ __launch_bounds__(256) void select_block(
    const float* __restrict__ part, float* __restrict__ xi,
    const float* __restrict__ conv_b, const float* __restrict__ bn_gamma,
    const float* __restrict__ bn_beta, const float* __restrict__ comb_w,
    const int* __restrict__ kptr) {
  const int t = threadIdx.x;
  const int lane = t & 63, wid = t >> 6;
  const int bh = blockIdx.x;
  const int h = bh & (NH - 1);
  __shared__ float xs[LP];
  __shared__ float smp[NL + 2];  // m shifted by 2, zero-padded both ends
  __shared__ int hist[256];
  __shared__ float rs[8];
  __shared__ float fbc[2];
  __shared__ int irs[8];
  __shared__ int ibc[4];

  const float cb = conv_b[h];
  const float* p0 = part + (size_t)bh * NCHUNK * NL;
  float s1 = 0.f, s2 = 0.f;
  for (int i = t; i < LP; i += 256) {
    float v = cb;
#pragma unroll
    for (int k = 0; k < NCHUNK; k += 4)
      v += ((p0[i + (size_t)k * NL] + p0[i + (size_t)(k + 1) * NL]) +
            (p0[i + (size_t)(k + 2) * NL] + p0[i + (size_t)(k + 3) * NL]));
    xs[i] = v;
    s1 += v;
    s2 += v * v;
  }
#pragma unroll
  for (int off = 32; off > 0; off >>= 1) {
    s1 += __shfl_down(s1, off);
    s2 += __shfl_down(s2, off);
  }
  if (lane == 0) { rs[wid] = s1; rs[wid + 4] = s2; }
  __syncthreads();
  if (t == 0) {
    float S = rs[0] + rs[1] + rs[2] + rs[3];
    float Q = rs[4] + rs[5] + rs[6] + rs[7];
    float mu = S / (float)LP;
    float var = Q / (float)LP - mu * mu;
    float inv = rsqrtf(var + 1e-5f);
    float sc = bn_gamma[h] * inv;
    fbc[0] = sc;
    fbc[1] = bn_beta[h] - mu * sc;
  }
  __syncthreads();
  {
    const float sc = fbc[0], sh = fbc[1];
    for (int i = t; i < LP; i += 256) xs[i] = fmaf(xs[i], sc, sh);
  }
  // exact radix select of the k-th largest key (4x 8-bit passes)
  int kk = kptr[0];
  const int ktot = kk;
  unsigned prefix = 0, pm = 0;
  for (int pass = 0; pass < 4; ++pass) {
    const int shift = 24 - 8 * pass;
    hist[t] = 0;
    __syncthreads();
    for (int i = t; i < LP; i += 256) {
      unsigned u = fkey(xs[i]);
      if ((u & pm) == prefix) atomicAdd(&hist[(u >> shift) & 255], 1);
    }
    __syncthreads();
    if (t < 64) {  // wave 0: suffix-scan 256 bins, 4 bins/lane
      const int h0 = hist[t * 4 + 0], h1 = hist[t * 4 + 1];
      const int h2 = hist[t * 4 + 2], h3 = hist[t * 4 + 3];
      const int g = h0 + h1 + h2 + h3;
      int sfx = g;
#pragma unroll
      for (int off = 1; off < 64; off <<= 1) {
        int o = __shfl(sfx, (t + off) & 63);
        if (t + off < 64) sfx += o;
      }
      const int A = sfx - g;  // strictly-higher groups
      const int s3 = A + h3, s2i = s3 + h2, s1i = s2i + h1, s0i = s1i + h0;
      int mybin = -1, mykk = 0;
      if (s0i >= kk && s0i - h0 < kk) { mybin = t * 4 + 0; mykk = kk - (s0i - h0); }
      if (s1i >= kk && s1i - h1 < kk) { mybin = t * 4 + 1; mykk = kk - (s1i - h1); }
      if (s2i >= kk && s2i - h2 < kk) { mybin = t * 4 + 2; mykk = kk - (s2i - h2); }
      if (s3  >= kk && s3  - h3 < kk) { mybin = t * 4 + 3; mykk = kk - (s3 - h3); }
      if (mybin >= 0) { ibc[0] = mybin; ibc[1] = mykk; }  // unique crossing
    }
    __syncthreads();
    prefix |= ((unsigned)ibc[0]) << shift;
    pm |= 255u << shift;
    kk = ibc[1];
  }
  const unsigned T = prefix;

  // counts for tie handling
  int cgt = 0, ceq = 0;
  for (int i = t; i < LP; i += 256) {
    unsigned u = fkey(xs[i]);
    cgt += (u > T);
    ceq += (u == T);
  }
#pragma unroll
  for (int off = 32; off > 0; off >>= 1) {
    cgt += __shfl_down(cgt, off);
    ceq += __shfl_down(ceq, off);
  }
  if (lane == 0) { irs[wid] = cgt; irs[wid + 4] = ceq; }
  __syncthreads();
  if (t == 0) {
    ibc[2] = irs[0] + irs[1] + irs[2] + irs[3];
    ibc[3] = irs[4] + irs[5] + irs[6] + irs[7];
  }
  __syncthreads();
  const int need_eq = ktot - ibc[2];
  const bool tie = (ibc[3] != need_eq);

  // mask + sigmoid -> smp (shifted by 2)
  for (int i = t; i < LP; i += 256) {
    float x = xs[i];
    unsigned u = fkey(x);
    bool sel = tie ? (u > T) : (u >= T);
    smp[i + 2] = sel ? 1.f / (1.f + __expf(-x)) : 0.f;
  }
  if (t < 2) { smp[t] = 0.f; smp[NL + t] = 0.f; }
  __syncthreads();
  if (tie && t == 0) {  // rare: stable lowest-index-first like lax.top_k
    int taken = 0;
    for (int i = 0; i < LP && taken < need_eq; ++i) {
      float x = xs[i];
      if (fkey(x) == T) { smp[i + 2] = 1.f / (1.f + __expf(-x)); ++taken; }
    }
  }
  __syncthreads();

  // 3-tap box sum; write this head's gate contribution
  const float cw = comb_w[h] * (1.0f / (float)KW);
  float* row = xi + (size_t)bh * NL;
  for (int l = t; l < NL; l += 256)
    row[l] = cw * ((smp[l + 2] + smp[l + 1]) + smp[l]);
}

// Kernel 3 (R8-proven): each thread owns one (b,l4) pair, computes the
// 8-head gate sum ONCE, reuses it across 16 channels of coalesced
// src-load + NT-store.
__global__ __launch_bounds__(256) void scale_gate(
    const float* __restrict__ src, const float* __restrict__ xi,
    const float* __restrict__ comb_b, float* __restrict__ out) {
  const int t = threadIdx.x;
  const int cchunk = blockIdx.x >> 7;               // 0..15, 16 channels each
  const int pairidx = (blockIdx.x & 127) * 256 + t; // 0..32767
  const int b = pairidx >> 9;                       // NL/4 = 512 l4 per b
  const int l4 = pairidx & 511;
  const float cb = comb_b[0];

  const v4f* xp = (const v4f*)(xi + (size_t)b * NH * NL) + l4;
  v4f g = xp[0];
#pragma unroll
  for (int h = 1; h < NH; ++h) g += xp[(size_t)h * (NL / 4)];

  const int c0 = cchunk * (NC / 16);
  const v4f* sp = (const v4f*)src + ((size_t)b * NC + c0) * (NL / 4) + l4;
  v4f* op = (v4f*)out + ((size_t)b * NC + c0) * (NL / 4) + l4;
#pragma unroll 4
  for (int c = 0; c < NC / 16; ++c) {
    v4f sv = sp[(size_t)c * (NL / 4)];
    v4f ov;
    ov.x = fmaf(sv.x, g.x, cb);
    ov.y = fmaf(sv.y, g.y, cb);
    ov.z = fmaf(sv.z, g.z, cb);
    ov.w = fmaf(sv.w, g.w, cb);
    __builtin_nontemporal_store(ov, op + (size_t)c * (NL / 4));
  }
}

extern "C" void kernel_launch(void* const* d_in, const int* in_sizes, int n_in,
                              void* d_out, int out_size, void* d_ws, size_t ws_size,
                              hipStream_t stream) {
  const float* src = (const float*)d_in[0];
  const float* conv_w = (const float*)d_in[1];
  const float* conv_b = (const float*)d_in[2];
  const float* bn_gamma = (const float*)d_in[3];
  const float* bn_beta = (const float*)d_in[4];
  const float* comb_w = (const float*)d_in[5];
  const float* comb_b = (const float*)d_in[6];
  const int* kptr = (const int*)d_in[7];
  float* out = (float*)d_out;

  float* xi = (float*)d_ws;  // NB*NH*NL floats (4 MB)
  float* part = out;         // 64 MB scratch inside d_out (134 MB): consumed
                             // by select_block, then overwritten by scale_gate

  conv_partial<<<dim3(2, NB, NCHUNK), 256, 0, stream>>>(src, conv_w, part);
  select_block<<<NB * NH, 256, 0, stream>>>(part, xi, conv_b, bn_gamma,
                                            bn_beta, comb_w, kptr);
  scale_gate<<<2048, 256, 0, stream>>>(src, xi, comb_b, out);
}

// Round 10
// 94.789 us; speedup vs baseline: 1.0620x; 1.0620x over previous
//
#include <hip/hip_runtime.h>
#include <hip/hip_bf16.h>

#define NB 64
#define NC 256
#define NL 2048
#define NH 8
#define KW 3
#define LP (NL - KW + 1)  // 2046
#define NCHUNK 8
#define CPC (NC / NCHUNK)  // 32 channels per chunk

typedef float v4f __attribute__((ext_vector_type(4)));

// monotonic float->uint key: order(u) == order(x)
__device__ __forceinline__ unsigned fkey(float x) {
  unsigned b = __float_as_uint(x);
  return (b & 0x80000000u) ? ~b : (b | 0x80000000u);
}

// Kernel 1 (R8 skeleton + LDS weights): conv1d partial sums. Each thread: 4
// consecutive l outputs x 8 heads from ONE float4 load per channel
// (+shuffle halo). NEW: chunk weights (CPC*8*3 floats) staged in LDS once
// per block -> per-iteration weight reads are uniform-address LDS
// broadcasts instead of s_loads (R1/R3 counters showed the scalar-load
// path serialized the loop: VALUBusy 11-14%, SGPR 112).
__global__ __launch_bounds__(256) void conv_partial(
    const float* __restrict__ src, const float* __restrict__ conv_w,
    float* __restrict__ part) {
  const int t = threadIdx.x;
  const int lane = t & 63;
  const int l0 = blockIdx.x * 1024 + t * 4;
  const int b = blockIdx.y;
  const int cc = blockIdx.z;
  const int c0 = cc * CPC;

  // stage this chunk's weights: wlds[c][h*3+k]
  __shared__ float wlds[CPC][24];
  for (int i = t; i < CPC * 24; i += 256) {
    const int ci = i / 24, r = i - ci * 24;
    const int h = r / 3, k = r - h * 3;
    wlds[ci][r] = conv_w[h * (NC * KW) + (c0 + ci) * KW + k];
  }
  __syncthreads();

  float acc[NH][4];
#pragma unroll
  for (int h = 0; h < NH; ++h)
#pragma unroll
    for (int j = 0; j < 4; ++j) acc[h][j] = 0.f;

  const float* sp = src + ((size_t)b * NC + c0) * NL + l0;
  const bool tail = (lane == 63) && (l0 + 5 < NL);
#pragma unroll 2
  for (int c = 0; c < CPC; ++c) {
    v4f v = *(const v4f*)sp;
    float e0 = 0.f, e1 = 0.f;
    if (tail) { e0 = sp[4]; e1 = sp[5]; }
    sp += NL;
    float n0 = __shfl_down(v.x, 1);
    float n1 = __shfl_down(v.y, 1);
    if (lane == 63) { n0 = e0; n1 = e1; }
    float s0 = v.x, s1 = v.y, s2 = v.z, s3 = v.w, s4 = n0, s5 = n1;
#pragma unroll
    for (int h = 0; h < NH; ++h) {
      const float w0 = wlds[c][h * 3 + 0];
      const float w1 = wlds[c][h * 3 + 1];
      const float w2 = wlds[c][h * 3 + 2];
      acc[h][0] = fmaf(s0, w0, fmaf(s1, w1, fmaf(s2, w2, acc[h][0])));
      acc[h][1] = fmaf(s1, w0, fmaf(s2, w1, fmaf(s3, w2, acc[h][1])));
      acc[h][2] = fmaf(s2, w0, fmaf(s3, w1, fmaf(s4, w2, acc[h][2])));
      acc[h][3] = fmaf(s3, w0, fmaf(s4, w1, fmaf(s5, w2, acc[h][3])));
    }
  }
#pragma unroll
  for (int h = 0; h < NH; ++h) {
    float* pr = part + ((size_t)(b * NH + h) * NCHUNK + cc) * NL + l0;
    if (l0 + 3 < LP) {
      *(v4f*)pr = *(v4f*)acc[h];
    } else {
#pragma unroll
      for (int j = 0; j < 4; ++j)
        if (l0 + j < LP) pr[j] = acc[h][j];
    }
  }
}

// Kernel 2 (R6/R8-proven, unchanged): one 256-thread block per (b,h). Sum 8
// partials (+bias) into LDS, BN stats, exact radix-select of the k-th
// largest (stable ties like lax.top_k), sigmoid mask, 3-tap box sum, write
// cw*M into the xi row.
__global__ __launch_bounds__(256) void select_block(
    const float* __restrict__ part, float* __restrict__ xi,
    const float* __restrict__ conv_b, const float* __restrict__ bn_gamma,
    const float* __restrict__ bn_beta, const float* __restrict__ comb_w,
    const int* __restrict__ kptr) {
  const int t = threadIdx.x;
  const int lane = t & 63, wid = t >> 6;
  const int bh = blockIdx.x;
  const int h = bh & (NH - 1);
  __shared__ float xs[LP];
  __shared__ float smp[NL + 2];  // m shifted by 2, zero-padded both ends
  __shared__ int hist[256];
  __shared__ float rs[8];
  __shared__ float fbc[2];
  __shared__ int irs[8];
  __shared__ int ibc[4];

  const float cb = conv_b[h];
  const float* p0 = part + (size_t)bh * NCHUNK * NL;
  float s1 = 0.f, s2 = 0.f;
  for (int i = t; i < LP; i += 256) {
    float v0 = p0[i]           + p0[i + NL];
    float v1 = p0[i + 2 * NL]  + p0[i + 3 * NL];
    float v2 = p0[i + 4 * NL]  + p0[i + 5 * NL];
    float v3 = p0[i + 6 * NL]  + p0[i + 7 * NL];
    float v = ((v0 + v1) + (v2 + v3)) + cb;
    xs[i] = v;
    s1 += v;
    s2 += v * v;
  }
#pragma unroll
  for (int off = 32; off > 0; off >>= 1) {
    s1 += __shfl_down(s1, off);
    s2 += __shfl_down(s2, off);
  }
  if (lane == 0) { rs[wid] = s1; rs[wid + 4] = s2; }
  __syncthreads();
  if (t == 0) {
    float S = rs[0] + rs[1] + rs[2] + rs[3];
    float Q = rs[4] + rs[5] + rs[6] + rs[7];
    float mu = S / (float)LP;
    float var = Q / (float)LP - mu * mu;
    float inv = rsqrtf(var + 1e-5f);
    float sc = bn_gamma[h] * inv;
    fbc[0] = sc;
    fbc[1] = bn_beta[h] - mu * sc;
  }
  __syncthreads();
  {
    const float sc = fbc[0], sh = fbc[1];
    for (int i = t; i < LP; i += 256) xs[i] = fmaf(xs[i], sc, sh);
  }
  // exact radix select of the k-th largest key (4x 8-bit passes)
  int kk = kptr[0];
  const int ktot = kk;
  unsigned prefix = 0, pm = 0;
  for (int pass = 0; pass < 4; ++pass) {
    const int shift = 24 - 8 * pass;
    hist[t] = 0;
    __syncthreads();
    for (int i = t; i < LP; i += 256) {
      unsigned u = fkey(xs[i]);
      if ((u & pm) == prefix) atomicAdd(&hist[(u >> shift) & 255], 1);
    }
    __syncthreads();
    if (t < 64) {  // wave 0: suffix-scan 256 bins, 4 bins/lane
      const int h0 = hist[t * 4 + 0], h1 = hist[t * 4 + 1];
      const int h2 = hist[t * 4 + 2], h3 = hist[t * 4 + 3];
      const int g = h0 + h1 + h2 + h3;
      int sfx = g;
#pragma unroll
      for (int off = 1; off < 64; off <<= 1) {
        int o = __shfl(sfx, (t + off) & 63);
        if (t + off < 64) sfx += o;
      }
      const int A = sfx - g;  // strictly-higher groups
      const int s3 = A + h3, s2i = s3 + h2, s1i = s2i + h1, s0i = s1i + h0;
      int mybin = -1, mykk = 0;
      if (s0i >= kk && s0i - h0 < kk) { mybin = t * 4 + 0; mykk = kk - (s0i - h0); }
      if (s1i >= kk && s1i - h1 < kk) { mybin = t * 4 + 1; mykk = kk - (s1i - h1); }
      if (s2i >= kk && s2i - h2 < kk) { mybin = t * 4 + 2; mykk = kk - (s2i - h2); }
      if (s3  >= kk && s3  - h3 < kk) { mybin = t * 4 + 3; mykk = kk - (s3 - h3); }
      if (mybin >= 0) { ibc[0] = mybin; ibc[1] = mykk; }  // unique crossing
    }
    __syncthreads();
    prefix |= ((unsigned)ibc[0]) << shift;
    pm |= 255u << shift;
    kk = ibc[1];
  }
  const unsigned T = prefix;

  // counts for tie handling
  int cgt = 0, ceq = 0;
  for (int i = t; i < LP; i += 256) {
    unsigned u = fkey(xs[i]);
    cgt += (u > T);
    ceq += (u == T);
  }
#pragma unroll
  for (int off = 32; off > 0; off >>= 1) {
    cgt += __shfl_down(cgt, off);
    ceq += __shfl_down(ceq, off);
  }
  if (lane == 0) { irs[wid] = cgt; irs[wid + 4] = ceq; }
  __syncthreads();
  if (t == 0) {
    ibc[2] = irs[0] + irs[1] + irs[2] + irs[3];
    ibc[3] = irs[4] + irs[5] + irs[6] + irs[7];
  }
  __syncthreads();
  const int need_eq = ktot - ibc[2];
  const bool tie = (ibc[3] != need_eq);

  // mask + sigmoid -> smp (shifted by 2)
  for (int i = t; i < LP; i += 256) {
    float x = xs[i];
    unsigned u = fkey(x);
    bool sel = tie ? (u > T) : (u >= T);
    smp[i + 2] = sel ? 1.f / (1.f + __expf(-x)) : 0.f;
  }
  if (t < 2) { smp[t] = 0.f; smp[NL + t] = 0.f; }
  __syncthreads();
  if (tie && t == 0) {  // rare: stable lowest-index-first like lax.top_k
    int taken = 0;
    for (int i = 0; i < LP && taken < need_eq; ++i) {
      float x = xs[i];
      if (fkey(x) == T) { smp[i + 2] = 1.f / (1.f + __expf(-x)); ++taken; }
    }
  }
  __syncthreads();

  // 3-tap box sum; write this head's gate contribution
  const float cw = comb_w[h] * (1.0f / (float)KW);
  float* row = xi + (size_t)bh * NL;
  for (int l = t; l < NL; l += 256)
    row[l] = cw * ((smp[l + 2] + smp[l + 1]) + smp[l]);
}

// Kernel 3 (R8-proven, unchanged): each thread owns one (b,l4) pair,
// computes the 8-head gate sum ONCE, reuses it across 16 channels of
// coalesced src-load + NT-store.
__global__ __launch_bounds__(256) void scale_gate(
    const float* __restrict__ src, const float* __restrict__ xi,
    const float* __restrict__ comb_b, float* __restrict__ out) {
  const int t = threadIdx.x;
  const int cchunk = blockIdx.x >> 7;               // 0..15, 16 channels each
  const int pairidx = (blockIdx.x & 127) * 256 + t; // 0..32767
  const int b = pairidx >> 9;                       // NL/4 = 512 l4 per b
  const int l4 = pairidx & 511;
  const float cb = comb_b[0];

  const v4f* xp = (const v4f*)(xi + (size_t)b * NH * NL) + l4;
  v4f g = xp[0];
#pragma unroll
  for (int h = 1; h < NH; ++h) g += xp[(size_t)h * (NL / 4)];

  const int c0 = cchunk * (NC / 16);
  const v4f* sp = (const v4f*)src + ((size_t)b * NC + c0) * (NL / 4) + l4;
  v4f* op = (v4f*)out + ((size_t)b * NC + c0) * (NL / 4) + l4;
#pragma unroll 4
  for (int c = 0; c < NC / 16; ++c) {
    v4f sv = sp[(size_t)c * (NL / 4)];
    v4f ov;
    ov.x = fmaf(sv.x, g.x, cb);
    ov.y = fmaf(sv.y, g.y, cb);
    ov.z = fmaf(sv.z, g.z, cb);
    ov.w = fmaf(sv.w, g.w, cb);
    __builtin_nontemporal_store(ov, op + (size_t)c * (NL / 4));
  }
}

extern "C" void kernel_launch(void* const* d_in, const int* in_sizes, int n_in,
                              void* d_out, int out_size, void* d_ws, size_t ws_size,
                              hipStream_t stream) {
  const float* src = (const float*)d_in[0];
  const float* conv_w = (const float*)d_in[1];
  const float* conv_b = (const float*)d_in[2];
  const float* bn_gamma = (const float*)d_in[3];
  const float* bn_beta = (const float*)d_in[4];
  const float* comb_w = (const float*)d_in[5];
  const float* comb_b = (const float*)d_in[6];
  const int* kptr = (const int*)d_in[7];
  float* out = (float*)d_out;

  float* xi = (float*)d_ws;  // NB*NH*NL floats (4 MB)
  float* part = out;         // 32 MB scratch inside d_out: consumed by
                             // select_block, then overwritten by scale_gate

  conv_partial<<<dim3(2, NB, NCHUNK), 256, 0, stream>>>(src, conv_w, part);
  select_block<<<NB * NH, 256, 0, stream>>>(part, xi, conv_b, bn_gamma,
                                            bn_beta, comb_w, kptr);
  scale_gate<<<2048, 256, 0, stream>>>(src, xi, comb_b, out);
}